// Round 6
// baseline (615.507 us; speedup 1.0000x reference)
//
#include <hip/hip_runtime.h>
#include <hip/hip_cooperative_groups.h>
#include <hip/hip_bf16.h>
#include <math.h>

namespace cg = cooperative_groups;

#define B_   32
#define S_   512
#define SxS  (S_ * S_)
#define LOG2E 1.4426950408889634f

using frag_ab = __attribute__((ext_vector_type(8))) short;   // 8 bf16 = 4 VGPR
using frag_cd = __attribute__((ext_vector_type(4))) float;   // 4 fp32 acc

__device__ inline short f2bf(float x) {
    __hip_bfloat16 h = __float2bfloat16(x);
    return *reinterpret_cast<short*>(&h);
}
__device__ inline float bf2f(short s) {
    __hip_bfloat16 h = *reinterpret_cast<__hip_bfloat16*>(&s);
    return __bfloat162float(h);
}
__device__ __forceinline__ int swz(int r) { return (r ^ (r >> 3)) & 7; }

__device__ __forceinline__ void async16(const short* g, short* l) {
    __builtin_amdgcn_global_load_lds(
        (const __attribute__((address_space(1))) void*)g,
        (__attribute__((address_space(3))) void*)l,
        16, 0, 0);
}

// ===========================================================================
// MEGA: entire pipeline in ONE cooperative kernel. 256 blocks x 256 thr
// (1 block/CU, co-resident). Phases separated by grid.sync():
//   P: prep (hi/lo planes + V-planes)        [old grid 4096 -> 16 iters]
//   G: e-GEMM (hi/lo bf16 MFMA) -> E         [old grid  512 ->  2 iters]
//   S: row stats + col stats                 [old 4096+256 -> 16+1 iters]
//   V: P-build + P·V GEMM + fused epilogue   [old grid 2048 ->  8 iters]
// ===========================================================================
__global__ __launch_bounds__(256) void k_mega(const float* __restrict__ A,
                                              const float* __restrict__ Bm,
                                              short* __restrict__ PA,
                                              short* __restrict__ PB,
                                              short* __restrict__ Va,
                                              short* __restrict__ Vb,
                                              float* __restrict__ E,
                                              float* __restrict__ rmax,
                                              float* __restrict__ rinv,
                                              float* __restrict__ cmax,
                                              float* __restrict__ cinv,
                                              float* __restrict__ Ma,
                                              float* __restrict__ Mb)
{
    cg::grid_group grid = cg::this_grid();
    const int pb  = blockIdx.x;       // 0..255
    const int tid = threadIdx.x;

    __shared__ __align__(16) char smem[65792];

    // ======================= Phase P: prep =================================
    {
        short (*T)[72] = (short(*)[72])smem;
        const int sl = tid & 7;
        const int il = tid >> 3;
        const int pc = tid & 7, dl = tid >> 3;

        for (int lin = pb; lin < 4096; lin += 256) {
            __syncthreads();
            const int bx = lin & 7, by = (lin >> 3) & 7, z = lin >> 6;
            const int b   = z & 31;
            const int isB = z >> 5;
            const float* X = (isB ? Bm : A) + (size_t)b * SxS;
            short* P  = (isB ? PB : PA) + (size_t)b * (S_ * 1024);
            short* Vp = (isB ? Vb : Va) + (size_t)b * SxS;
            const float scale = isB ? 1.0f : LOG2E;
            const int i0 = by * 64, d0 = bx * 64;

            #pragma unroll
            for (int pp = 0; pp < 2; ++pp) {
                const int i    = il + 32 * pp;
                const int rowg = i0 + i;
                const float* src = X + (size_t)rowg * S_ + d0 + sl * 8;
                const float4 v0 = *(const float4*)(src);
                const float4 v1 = *(const float4*)(src + 4);

                T[sl * 8 + 0][i] = f2bf(v0.x); T[sl * 8 + 1][i] = f2bf(v0.y);
                T[sl * 8 + 2][i] = f2bf(v0.z); T[sl * 8 + 3][i] = f2bf(v0.w);
                T[sl * 8 + 4][i] = f2bf(v1.x); T[sl * 8 + 5][i] = f2bf(v1.y);
                T[sl * 8 + 6][i] = f2bf(v1.z); T[sl * 8 + 7][i] = f2bf(v1.w);

                const float xs[8] = {v0.x, v0.y, v0.z, v0.w, v1.x, v1.y, v1.z, v1.w};
                frag_ab hi, lo;
                #pragma unroll
                for (int j = 0; j < 8; ++j) {
                    const float x = xs[j] * scale;
                    const short h = f2bf(x);
                    hi[j] = h;
                    lo[j] = f2bf(x - bf2f(h));
                }
                const int W = (d0 >> 5) + (sl >> 2);
                const int q = sl & 3;
                short* base = P + (size_t)rowg * 1024 + W * 64;
                *(frag_ab*)(base + (((2 * q)     ^ (rowg & 7)) * 8)) = hi;
                *(frag_ab*)(base + (((2 * q + 1) ^ (rowg & 7)) * 8)) = lo;
            }
            __syncthreads();

            #pragma unroll
            for (int pp = 0; pp < 2; ++pp) {
                const int d  = dl + 32 * pp;
                const int dg = d0 + d;
                frag_ab t = *(const frag_ab*)&T[d][pc * 8];
                *(frag_ab*)(Vp + (size_t)dg * 512 + i0 + ((pc ^ (dg & 7)) * 8)) = t;
            }
        }
    }
    __syncthreads();
    grid.sync();

    // ======================= Phase G: e-GEMM ===============================
    {
        short (*As)[64] = (short(*)[64])smem;
        short (*Bs)[64] = (short(*)[64])(smem + 16384);

        const int wave = tid >> 6, lane = tid & 63;
        const int wr   = wave >> 1, wc = wave & 1;
        const int q    = lane >> 4, m = lane & 15;
        const int srow = lane >> 3, schunk = lane & 7;

        for (int lin = pb; lin < 512; lin += 256) {
            const int logical = ((lin & 7) << 6) + (lin >> 3);
            const int b  = logical >> 4;
            const int i0 = ((logical >> 2) & 3) * 128;
            const int j0 = (logical & 3) * 128;

            const short* Ab = PA + (size_t)b * (S_ * 1024);
            const short* Bb = PB + (size_t)b * (S_ * 1024);
            float* Eb = E + (size_t)b * SxS;

            frag_cd zero = {0.f, 0.f, 0.f, 0.f};
            frag_cd acc[4][4];
            #pragma unroll
            for (int i = 0; i < 4; ++i)
                #pragma unroll
                for (int j = 0; j < 4; ++j) acc[i][j] = zero;

            for (int k0 = 0; k0 < S_; k0 += 32) {
                const int W = k0 >> 5;
                __syncthreads();
                #pragma unroll
                for (int p = 0; p < 4; ++p) {
                    const int seg    = wave * 4 + p;
                    const int rowg_a = i0 + seg * 8 + srow;
                    const int rowg_b = j0 + seg * 8 + srow;
                    async16(Ab + (size_t)rowg_a * 1024 + W * 64 + schunk * 8, &As[seg * 8][0]);
                    async16(Bb + (size_t)rowg_b * 1024 + W * 64 + schunk * 8, &Bs[seg * 8][0]);
                }
                __syncthreads();

                frag_ab ah[4], al[4], bh[4], bl[4];
                #pragma unroll
                for (int t = 0; t < 4; ++t) {
                    const int ra = wr * 64 + t * 16 + m;
                    const int rb = wc * 64 + t * 16 + m;
                    ah[t] = *(const frag_ab*)&As[ra][((2 * q)     ^ (ra & 7)) * 8];
                    al[t] = *(const frag_ab*)&As[ra][((2 * q + 1) ^ (ra & 7)) * 8];
                    bh[t] = *(const frag_ab*)&Bs[rb][((2 * q)     ^ (rb & 7)) * 8];
                    bl[t] = *(const frag_ab*)&Bs[rb][((2 * q + 1) ^ (rb & 7)) * 8];
                }
                #pragma unroll
                for (int mt = 0; mt < 4; ++mt)
                    #pragma unroll
                    for (int nt = 0; nt < 4; ++nt) {
                        acc[mt][nt] = __builtin_amdgcn_mfma_f32_16x16x32_bf16(ah[mt], bh[nt], acc[mt][nt], 0, 0, 0);
                        acc[mt][nt] = __builtin_amdgcn_mfma_f32_16x16x32_bf16(ah[mt], bl[nt], acc[mt][nt], 0, 0, 0);
                        acc[mt][nt] = __builtin_amdgcn_mfma_f32_16x16x32_bf16(al[mt], bh[nt], acc[mt][nt], 0, 0, 0);
                    }
            }

            #pragma unroll
            for (int mt = 0; mt < 4; ++mt)
                #pragma unroll
                for (int nt = 0; nt < 4; ++nt) {
                    const int rb  = i0 + wr * 64 + mt * 16 + q * 4;
                    const int col = j0 + wc * 64 + nt * 16 + m;
                    Eb[(size_t)(rb + 0) * S_ + col] = acc[mt][nt][0];
                    Eb[(size_t)(rb + 1) * S_ + col] = acc[mt][nt][1];
                    Eb[(size_t)(rb + 2) * S_ + col] = acc[mt][nt][2];
                    Eb[(size_t)(rb + 3) * S_ + col] = acc[mt][nt][3];
                }
            __syncthreads();
        }
    }
    grid.sync();

    // ======================= Phase S: stats ================================
    {
        const int lane = tid & 63;
        for (int lin = pb; lin < 4096; lin += 256) {
            const int row = lin * 4 + (tid >> 6);
            const float* er = E + (size_t)row * S_;

            float4 v0 = *(const float4*)(er + lane * 4);
            float4 v1 = *(const float4*)(er + 256 + lane * 4);

            float m = fmaxf(fmaxf(fmaxf(v0.x, v0.y), fmaxf(v0.z, v0.w)),
                            fmaxf(fmaxf(v1.x, v1.y), fmaxf(v1.z, v1.w)));
            #pragma unroll
            for (int off = 32; off >= 1; off >>= 1)
                m = fmaxf(m, __shfl_xor(m, off));

            float s = exp2f(v0.x - m) + exp2f(v0.y - m)
                    + exp2f(v0.z - m) + exp2f(v0.w - m)
                    + exp2f(v1.x - m) + exp2f(v1.y - m)
                    + exp2f(v1.z - m) + exp2f(v1.w - m);
            #pragma unroll
            for (int off = 32; off >= 1; off >>= 1)
                s += __shfl_xor(s, off);

            if (lane == 0) { rmax[row] = m; rinv[row] = 1.0f / s; }
        }

        float (*scr)[64] = (float(*)[64])smem;
        float* mS = (float*)(smem + 8192);

        const int b  = pb >> 3;
        const int s0 = (pb & 7) * 64;
        const float* Eb = E + (size_t)b * SxS;

        const int ib  = tid >> 3;
        const int sub = tid & 7;

        __syncthreads();
        float pm[8];
        #pragma unroll
        for (int c = 0; c < 8; ++c) pm[c] = -INFINITY;
        for (int ii = 0; ii < 16; ++ii) {
            const float* p = Eb + (size_t)(ib * 16 + ii) * S_ + s0 + sub * 8;
            const float4 u  = *(const float4*)p;
            const float4 u2 = *(const float4*)(p + 4);
            pm[0] = fmaxf(pm[0], u.x);  pm[1] = fmaxf(pm[1], u.y);
            pm[2] = fmaxf(pm[2], u.z);  pm[3] = fmaxf(pm[3], u.w);
            pm[4] = fmaxf(pm[4], u2.x); pm[5] = fmaxf(pm[5], u2.y);
            pm[6] = fmaxf(pm[6], u2.z); pm[7] = fmaxf(pm[7], u2.w);
        }
        #pragma unroll
        for (int c = 0; c < 8; ++c) scr[ib][sub * 8 + c] = pm[c];
        __syncthreads();
        if (tid < 64) {
            float v = scr[0][tid];
            #pragma unroll
            for (int k = 1; k < 32; ++k) v = fmaxf(v, scr[k][tid]);
            mS[tid] = v;
            cmax[b * S_ + s0 + tid] = v;
        }
        __syncthreads();

        float ps[8];
        #pragma unroll
        for (int c = 0; c < 8; ++c) ps[c] = 0.f;
        for (int ii = 0; ii < 16; ++ii) {
            const float* p = Eb + (size_t)(ib * 16 + ii) * S_ + s0 + sub * 8;
            const float4 u  = *(const float4*)p;
            const float4 u2 = *(const float4*)(p + 4);
            const float xs[8] = {u.x, u.y, u.z, u.w, u2.x, u2.y, u2.z, u2.w};
            #pragma unroll
            for (int c = 0; c < 8; ++c) ps[c] += exp2f(xs[c] - mS[sub * 8 + c]);
        }
        __syncthreads();
        #pragma unroll
        for (int c = 0; c < 8; ++c) scr[ib][sub * 8 + c] = ps[c];
        __syncthreads();
        if (tid < 64) {
            float v = 0.f;
            #pragma unroll
            for (int k = 0; k < 32; ++k) v += scr[k][tid];
            cinv[b * S_ + s0 + tid] = 1.0f / v;
        }
        __syncthreads();
    }
    grid.sync();

    // ======================= Phase V: PV + epilogue ========================
    {
        short (*Pl)[512] = (short(*)[512])smem;            // 32 KB
        short (*Vs)[64]  = (short(*)[64])(smem + 32768);   // 32 KB
        float* riS       = (float*)(smem + 65536);

        const int wv = tid >> 6, lane = tid & 63;
        const int q  = lane >> 4, m = lane & 15;

        for (int lin = pb; lin < 2048; lin += 256) {
            __syncthreads();
            const int wg   = ((lin & 7) << 8) | (lin >> 3);
            const int side = wg >> 10;
            const int b    = (wg >> 5) & 31;
            const int rs   = (wg >> 1) & 15;
            const int dh   = wg & 1;
            const int s0   = rs * 32;

            const float* Eb  = E + (size_t)b * SxS;
            const float* pmx = (side ? cmax : rmax) + b * S_;
            const float* piv = (side ? cinv : rinv) + b * S_;
            const short* Vg  = (side ? Va : Vb) + (size_t)b * SxS;
            const float* Xb  = (side ? Bm : A) + (size_t)b * SxS;
            float* Ob = (side ? Mb : Ma) + (size_t)b * S_ * 2048;

            if (tid < 32) riS[tid] = piv[s0 + tid];

            if (side == 0) {
                const int rl = tid >> 3, sub = tid & 7;
                const float mx = pmx[s0 + rl];
                const float* er = Eb + (size_t)(s0 + rl) * S_;
                const int sl = (sub ^ swz(rl)) * 8;
                #pragma unroll
                for (int fi = 0; fi < 8; ++fi) {
                    const float* p = er + sub * 8 + fi * 64;
                    const float4 u  = *(const float4*)p;
                    const float4 u2 = *(const float4*)(p + 4);
                    const float xs[8] = {u.x, u.y, u.z, u.w, u2.x, u2.y, u2.z, u2.w};
                    frag_ab pbf;
                    #pragma unroll
                    for (int j = 0; j < 8; ++j) pbf[j] = f2bf(exp2f(xs[j] - mx));
                    *(frag_ab*)&Pl[rl][fi * 64 + sl] = pbf;
                }
            } else {
                const int ib = tid >> 2, cs = tid & 3;
                float mloc[8];
                #pragma unroll
                for (int c = 0; c < 8; ++c) mloc[c] = pmx[s0 + cs * 8 + c];
                frag_ab pbf[8];
                #pragma unroll
                for (int ii = 0; ii < 8; ++ii) {
                    const float* p = Eb + (size_t)(ib * 8 + ii) * S_ + s0 + cs * 8;
                    const float4 u  = *(const float4*)p;
                    const float4 u2 = *(const float4*)(p + 4);
                    const float xs[8] = {u.x, u.y, u.z, u.w, u2.x, u2.y, u2.z, u2.w};
                    #pragma unroll
                    for (int c = 0; c < 8; ++c)
                        pbf[c][ii] = f2bf(exp2f(xs[c] - mloc[c]));
                }
                #pragma unroll
                for (int c = 0; c < 8; ++c) {
                    const int cl = cs * 8 + c;
                    *(frag_ab*)&Pl[cl][((ib ^ swz(cl)) & 63) * 8] = pbf[c];
                }
            }

            frag_cd zero = {0.f, 0.f, 0.f, 0.f};
            frag_cd acc[2][4];
            #pragma unroll
            for (int i = 0; i < 2; ++i)
                #pragma unroll
                for (int j = 0; j < 4; ++j) acc[i][j] = zero;

            for (int k0 = 0; k0 < S_; k0 += 64) {
                __syncthreads();
                #pragma unroll
                for (int p = 0; p < 8; ++p) {
                    const int seg = p * 32 + wv * 8;
                    const int d   = dh * 256 + seg + (lane >> 3);
                    async16(Vg + (size_t)d * 512 + k0 + (lane & 7) * 8, &Vs[seg][0]);
                }
                __syncthreads();

                #pragma unroll
                for (int kk = 0; kk < 2; ++kk) {
                    frag_ab af[2], bf[4];
                    #pragma unroll
                    for (int t = 0; t < 2; ++t) {
                        const int ra = t * 16 + m;
                        af[t] = *(const frag_ab*)&Pl[ra][k0 + (((kk * 4 + q) ^ swz(ra)) * 8)];
                    }
                    #pragma unroll
                    for (int t = 0; t < 4; ++t) {
                        const int dl = wv * 64 + t * 16 + m;
                        bf[t] = *(const frag_ab*)&Vs[dl][(((kk * 4 + q) ^ (dl & 7)) * 8)];
                    }
                    #pragma unroll
                    for (int mt = 0; mt < 2; ++mt)
                        #pragma unroll
                        for (int nt = 0; nt < 4; ++nt)
                            acc[mt][nt] = __builtin_amdgcn_mfma_f32_16x16x32_bf16(af[mt], bf[nt], acc[mt][nt], 0, 0, 0);
                }
            }

            #pragma unroll
            for (int mt = 0; mt < 2; ++mt)
                #pragma unroll
                for (int nt = 0; nt < 4; ++nt) {
                    const int colg = dh * 256 + wv * 64 + nt * 16 + m;
                    #pragma unroll
                    for (int rr = 0; rr < 4; ++rr) {
                        const int rl   = mt * 16 + q * 4 + rr;
                        const int rowg = s0 + rl;
                        const float at = acc[mt][nt][rr] * riS[rl];
                        const float xv = Xb[(size_t)rowg * S_ + colg];
                        float* o = Ob + (size_t)rowg * 2048 + colg;
                        o[0]    = xv;
                        o[512]  = at;
                        o[1024] = xv - at;
                        o[1536] = xv * at;
                    }
                }
        }
    }
}

// ===========================================================================
// FALLBACK pipeline (R4, verified 475.7 µs) — used if cooperative launch
// is rejected by the runtime/graph-capture path.
// ===========================================================================
__global__ __launch_bounds__(256) void k_prep(const float* __restrict__ A,
                                              const float* __restrict__ Bm,
                                              short* __restrict__ PA,
                                              short* __restrict__ PB,
                                              short* __restrict__ Va,
                                              short* __restrict__ Vb)
{
    const int z   = blockIdx.z;
    const int b   = z & 31;
    const int isB = z >> 5;
    const float* X = (isB ? Bm : A) + (size_t)b * SxS;
    short* P  = (isB ? PB : PA) + (size_t)b * (S_ * 1024);
    short* Vp = (isB ? Vb : Va) + (size_t)b * SxS;
    const float scale = isB ? 1.0f : LOG2E;

    const int i0 = blockIdx.y * 64, d0 = blockIdx.x * 64;

    __shared__ short T[64][72];

    const int sl = threadIdx.x & 7;
    const int il = threadIdx.x >> 3;

    #pragma unroll
    for (int p = 0; p < 2; ++p) {
        const int i    = il + 32 * p;
        const int rowg = i0 + i;
        const float* src = X + (size_t)rowg * S_ + d0 + sl * 8;
        const float4 v0 = *(const float4*)(src);
        const float4 v1 = *(const float4*)(src + 4);

        T[sl * 8 + 0][i] = f2bf(v0.x); T[sl * 8 + 1][i] = f2bf(v0.y);
        T[sl * 8 + 2][i] = f2bf(v0.z); T[sl * 8 + 3][i] = f2bf(v0.w);
        T[sl * 8 + 4][i] = f2bf(v1.x); T[sl * 8 + 5][i] = f2bf(v1.y);
        T[sl * 8 + 6][i] = f2bf(v1.z); T[sl * 8 + 7][i] = f2bf(v1.w);

        const float xs[8] = {v0.x, v0.y, v0.z, v0.w, v1.x, v1.y, v1.z, v1.w};
        frag_ab hi, lo;
        #pragma unroll
        for (int j = 0; j < 8; ++j) {
            const float x = xs[j] * scale;
            const short h = f2bf(x);
            hi[j] = h;
            lo[j] = f2bf(x - bf2f(h));
        }
        const int W = (d0 >> 5) + (sl >> 2);
        const int q = sl & 3;
        short* base = P + (size_t)rowg * 1024 + W * 64;
        *(frag_ab*)(base + (((2 * q)     ^ (rowg & 7)) * 8)) = hi;
        *(frag_ab*)(base + (((2 * q + 1) ^ (rowg & 7)) * 8)) = lo;
    }
    __syncthreads();

    const int pc = threadIdx.x & 7, dl = threadIdx.x >> 3;
    #pragma unroll
    for (int p = 0; p < 2; ++p) {
        const int d  = dl + 32 * p;
        const int dg = d0 + d;
        frag_ab t = *(const frag_ab*)&T[d][pc * 8];
        *(frag_ab*)(Vp + (size_t)dg * 512 + i0 + ((pc ^ (dg & 7)) * 8)) = t;
    }
}

__global__ __launch_bounds__(256) void k_gemm_e(const short* __restrict__ PA,
                                                const short* __restrict__ PB,
                                                float* __restrict__ E)
{
    const int lin     = blockIdx.x + (blockIdx.y << 2) + (blockIdx.z << 4);
    const int logical = ((lin & 7) << 6) + (lin >> 3);
    const int b  = logical >> 4;
    const int i0 = ((logical >> 2) & 3) * 128;
    const int j0 = (logical & 3) * 128;

    const short* Ab = PA + (size_t)b * (S_ * 1024);
    const short* Bb = PB + (size_t)b * (S_ * 1024);
    float* Eb = E + (size_t)b * SxS;

    __shared__ __align__(16) short As[128][64];
    __shared__ __align__(16) short Bs[128][64];

    const int tid  = threadIdx.x;
    const int wave = tid >> 6, lane = tid & 63;
    const int wr   = wave >> 1, wc = wave & 1;
    const int q    = lane >> 4, m = lane & 15;
    const int srow = lane >> 3, schunk = lane & 7;

    frag_cd zero = {0.f, 0.f, 0.f, 0.f};
    frag_cd acc[4][4];
    #pragma unroll
    for (int i = 0; i < 4; ++i)
        #pragma unroll
        for (int j = 0; j < 4; ++j) acc[i][j] = zero;

    for (int k0 = 0; k0 < S_; k0 += 32) {
        const int W = k0 >> 5;
        __syncthreads();
        #pragma unroll
        for (int p = 0; p < 4; ++p) {
            const int seg    = wave * 4 + p;
            const int rowg_a = i0 + seg * 8 + srow;
            const int rowg_b = j0 + seg * 8 + srow;
            async16(Ab + (size_t)rowg_a * 1024 + W * 64 + schunk * 8, &As[seg * 8][0]);
            async16(Bb + (size_t)rowg_b * 1024 + W * 64 + schunk * 8, &Bs[seg * 8][0]);
        }
        __syncthreads();

        frag_ab ah[4], al[4], bh[4], bl[4];
        #pragma unroll
        for (int t = 0; t < 4; ++t) {
            const int ra = wr * 64 + t * 16 + m;
            const int rb = wc * 64 + t * 16 + m;
            ah[t] = *(const frag_ab*)&As[ra][((2 * q)     ^ (ra & 7)) * 8];
            al[t] = *(const frag_ab*)&As[ra][((2 * q + 1) ^ (ra & 7)) * 8];
            bh[t] = *(const frag_ab*)&Bs[rb][((2 * q)     ^ (rb & 7)) * 8];
            bl[t] = *(const frag_ab*)&Bs[rb][((2 * q + 1) ^ (rb & 7)) * 8];
        }
        #pragma unroll
        for (int mt = 0; mt < 4; ++mt)
            #pragma unroll
            for (int nt = 0; nt < 4; ++nt) {
                acc[mt][nt] = __builtin_amdgcn_mfma_f32_16x16x32_bf16(ah[mt], bh[nt], acc[mt][nt], 0, 0, 0);
                acc[mt][nt] = __builtin_amdgcn_mfma_f32_16x16x32_bf16(ah[mt], bl[nt], acc[mt][nt], 0, 0, 0);
                acc[mt][nt] = __builtin_amdgcn_mfma_f32_16x16x32_bf16(al[mt], bh[nt], acc[mt][nt], 0, 0, 0);
            }
    }

    #pragma unroll
    for (int mt = 0; mt < 4; ++mt)
        #pragma unroll
        for (int nt = 0; nt < 4; ++nt) {
            const int rb  = i0 + wr * 64 + mt * 16 + q * 4;
            const int col = j0 + wc * 64 + nt * 16 + m;
            Eb[(size_t)(rb + 0) * S_ + col] = acc[mt][nt][0];
            Eb[(size_t)(rb + 1) * S_ + col] = acc[mt][nt][1];
            Eb[(size_t)(rb + 2) * S_ + col] = acc[mt][nt][2];
            Eb[(size_t)(rb + 3) * S_ + col] = acc[mt][nt][3];
        }
}

__global__ __launch_bounds__(256) void k_rstats(const float* __restrict__ E,
                                                float* __restrict__ rmax,
                                                float* __restrict__ rinv)
{
    const int row  = blockIdx.x * 4 + (threadIdx.x >> 6);
    const int lane = threadIdx.x & 63;
    const float* er = E + (size_t)row * S_;

    float4 v0 = *(const float4*)(er + lane * 4);
    float4 v1 = *(const float4*)(er + 256 + lane * 4);

    float m = fmaxf(fmaxf(fmaxf(v0.x, v0.y), fmaxf(v0.z, v0.w)),
                    fmaxf(fmaxf(v1.x, v1.y), fmaxf(v1.z, v1.w)));
    #pragma unroll
    for (int off = 32; off >= 1; off >>= 1)
        m = fmaxf(m, __shfl_xor(m, off));

    float s = exp2f(v0.x - m) + exp2f(v0.y - m)
            + exp2f(v0.z - m) + exp2f(v0.w - m)
            + exp2f(v1.x - m) + exp2f(v1.y - m)
            + exp2f(v1.z - m) + exp2f(v1.w - m);
    #pragma unroll
    for (int off = 32; off >= 1; off >>= 1)
        s += __shfl_xor(s, off);

    if (lane == 0) { rmax[row] = m; rinv[row] = 1.0f / s; }
}

__global__ __launch_bounds__(256) void k_cstats(const float* __restrict__ E,
                                                float* __restrict__ cmax,
                                                float* __restrict__ cinv)
{
    const int b  = blockIdx.x >> 3;
    const int s0 = (blockIdx.x & 7) * 64;
    const float* Eb = E + (size_t)b * SxS;

    __shared__ float scr[32][64];
    __shared__ float mS[64];

    const int tid = threadIdx.x;
    const int ib  = tid >> 3;
    const int sub = tid & 7;

    float pm[8];
    #pragma unroll
    for (int c = 0; c < 8; ++c) pm[c] = -INFINITY;
    for (int ii = 0; ii < 16; ++ii) {
        const float* p = Eb + (size_t)(ib * 16 + ii) * S_ + s0 + sub * 8;
        const float4 u  = *(const float4*)p;
        const float4 u2 = *(const float4*)(p + 4);
        pm[0] = fmaxf(pm[0], u.x);  pm[1] = fmaxf(pm[1], u.y);
        pm[2] = fmaxf(pm[2], u.z);  pm[3] = fmaxf(pm[3], u.w);
        pm[4] = fmaxf(pm[4], u2.x); pm[5] = fmaxf(pm[5], u2.y);
        pm[6] = fmaxf(pm[6], u2.z); pm[7] = fmaxf(pm[7], u2.w);
    }
    #pragma unroll
    for (int c = 0; c < 8; ++c) scr[ib][sub * 8 + c] = pm[c];
    __syncthreads();
    if (tid < 64) {
        float v = scr[0][tid];
        #pragma unroll
        for (int k = 1; k < 32; ++k) v = fmaxf(v, scr[k][tid]);
        mS[tid] = v;
        cmax[b * S_ + s0 + tid] = v;
    }
    __syncthreads();

    float ps[8];
    #pragma unroll
    for (int c = 0; c < 8; ++c) ps[c] = 0.f;
    for (int ii = 0; ii < 16; ++ii) {
        const float* p = Eb + (size_t)(ib * 16 + ii) * S_ + s0 + sub * 8;
        const float4 u  = *(const float4*)p;
        const float4 u2 = *(const float4*)(p + 4);
        const float xs[8] = {u.x, u.y, u.z, u.w, u2.x, u2.y, u2.z, u2.w};
        #pragma unroll
        for (int c = 0; c < 8; ++c) ps[c] += exp2f(xs[c] - mS[sub * 8 + c]);
    }
    __syncthreads();
    #pragma unroll
    for (int c = 0; c < 8; ++c) scr[ib][sub * 8 + c] = ps[c];
    __syncthreads();
    if (tid < 64) {
        float v = 0.f;
        #pragma unroll
        for (int k = 0; k < 32; ++k) v += scr[k][tid];
        cinv[b * S_ + s0 + tid] = 1.0f / v;
    }
}

__global__ __launch_bounds__(256) void k_pv(const float* __restrict__ E,
                                            const float* __restrict__ rmx_,
                                            const float* __restrict__ rin_,
                                            const float* __restrict__ cmx_,
                                            const float* __restrict__ cin_,
                                            const short* __restrict__ Va,
                                            const short* __restrict__ Vb,
                                            const float* __restrict__ A,
                                            const float* __restrict__ Bm,
                                            float* __restrict__ Ma,
                                            float* __restrict__ Mb)
{
    const int lin = blockIdx.x;
    const int wg  = ((lin & 7) << 8) | (lin >> 3);
    const int side = wg >> 10;
    const int b    = (wg >> 5) & 31;
    const int rs   = (wg >> 1) & 15;
    const int dh   = wg & 1;
    const int s0   = rs * 32;

    const float* Eb  = E + (size_t)b * SxS;
    const float* pmx = (side ? cmx_ : rmx_) + b * S_;
    const float* piv = (side ? cin_ : rin_) + b * S_;
    const short* Vg  = (side ? Va : Vb) + (size_t)b * SxS;
    const float* Xb  = (side ? Bm : A) + (size_t)b * SxS;
    float* Ob = (side ? Mb : Ma) + (size_t)b * S_ * 2048;

    __shared__ __align__(16) short Pl[32][512];
    __shared__ __align__(16) short Vs[256][64];
    __shared__ float riS[32];

    const int tid = threadIdx.x;
    const int wv  = tid >> 6, lane = tid & 63;
    const int q   = lane >> 4, m = lane & 15;

    if (tid < 32) riS[tid] = piv[s0 + tid];

    if (side == 0) {
        const int rl = tid >> 3, sub = tid & 7;
        const float mx = pmx[s0 + rl];
        const float* er = Eb + (size_t)(s0 + rl) * S_;
        const int sl = (sub ^ swz(rl)) * 8;
        #pragma unroll
        for (int fi = 0; fi < 8; ++fi) {
            const float* p = er + sub * 8 + fi * 64;
            const float4 u  = *(const float4*)p;
            const float4 u2 = *(const float4*)(p + 4);
            const float xs[8] = {u.x, u.y, u.z, u.w, u2.x, u2.y, u2.z, u2.w};
            frag_ab pb;
            #pragma unroll
            for (int j = 0; j < 8; ++j) pb[j] = f2bf(exp2f(xs[j] - mx));
            *(frag_ab*)&Pl[rl][fi * 64 + sl] = pb;
        }
    } else {
        const int ib = tid >> 2, cs = tid & 3;
        float mloc[8];
        #pragma unroll
        for (int c = 0; c < 8; ++c) mloc[c] = pmx[s0 + cs * 8 + c];
        frag_ab pb[8];
        #pragma unroll
        for (int ii = 0; ii < 8; ++ii) {
            const float* p = Eb + (size_t)(ib * 8 + ii) * S_ + s0 + cs * 8;
            const float4 u  = *(const float4*)p;
            const float4 u2 = *(const float4*)(p + 4);
            const float xs[8] = {u.x, u.y, u.z, u.w, u2.x, u2.y, u2.z, u2.w};
            #pragma unroll
            for (int c = 0; c < 8; ++c)
                pb[c][ii] = f2bf(exp2f(xs[c] - mloc[c]));
        }
        #pragma unroll
        for (int c = 0; c < 8; ++c) {
            const int cl = cs * 8 + c;
            *(frag_ab*)&Pl[cl][((ib ^ swz(cl)) & 63) * 8] = pb[c];
        }
    }

    frag_cd zero = {0.f, 0.f, 0.f, 0.f};
    frag_cd acc[2][4];
    #pragma unroll
    for (int i = 0; i < 2; ++i)
        #pragma unroll
        for (int j = 0; j < 4; ++j) acc[i][j] = zero;

    for (int k0 = 0; k0 < S_; k0 += 64) {
        __syncthreads();
        #pragma unroll
        for (int p = 0; p < 8; ++p) {
            const int seg = p * 32 + wv * 8;
            const int d   = dh * 256 + seg + (lane >> 3);
            async16(Vg + (size_t)d * 512 + k0 + (lane & 7) * 8, &Vs[seg][0]);
        }
        __syncthreads();

        #pragma unroll
        for (int kk = 0; kk < 2; ++kk) {
            frag_ab af[2], bf[4];
            #pragma unroll
            for (int t = 0; t < 2; ++t) {
                const int ra = t * 16 + m;
                af[t] = *(const frag_ab*)&Pl[ra][k0 + (((kk * 4 + q) ^ swz(ra)) * 8)];
            }
            #pragma unroll
            for (int t = 0; t < 4; ++t) {
                const int dl = wv * 64 + t * 16 + m;
                bf[t] = *(const frag_ab*)&Vs[dl][(((kk * 4 + q) ^ (dl & 7)) * 8)];
            }
            #pragma unroll
            for (int mt = 0; mt < 2; ++mt)
                #pragma unroll
                for (int nt = 0; nt < 4; ++nt)
                    acc[mt][nt] = __builtin_amdgcn_mfma_f32_16x16x32_bf16(af[mt], bf[nt], acc[mt][nt], 0, 0, 0);
        }
    }

    #pragma unroll
    for (int mt = 0; mt < 2; ++mt)
        #pragma unroll
        for (int nt = 0; nt < 4; ++nt) {
            const int colg = dh * 256 + wv * 64 + nt * 16 + m;
            #pragma unroll
            for (int rr = 0; rr < 4; ++rr) {
                const int rl   = mt * 16 + q * 4 + rr;
                const int rowg = s0 + rl;
                const float at = acc[mt][nt][rr] * riS[rl];
                const float xv = Xb[(size_t)rowg * S_ + colg];
                float* o = Ob + (size_t)rowg * 2048 + colg;
                o[0]    = xv;
                o[512]  = at;
                o[1024] = xv - at;
                o[1536] = xv * at;
            }
        }
}

// ---------------------------------------------------------------------------
extern "C" void kernel_launch(void* const* d_in, const int* in_sizes, int n_in,
                              void* d_out, int out_size, void* d_ws, size_t ws_size,
                              hipStream_t stream)
{
    const float* A  = (const float*)d_in[0];   // a_bar [32,512,512]
    const float* Bm = (const float*)d_in[1];   // b_bar [32,512,512]
    float* Ma = (float*)d_out;                             // [32,512,2048]
    float* Mb = Ma + (size_t)B_ * S_ * 2048;               // [32,512,2048]

    float* E    = (float*)d_ws;
    short* Va   = (short*)(E + (size_t)B_ * SxS);
    short* Vb   = Va + (size_t)B_ * SxS;
    float* rmax = (float*)(Vb + (size_t)B_ * SxS);
    float* rinv = rmax + B_ * S_;
    float* cmax = rinv + B_ * S_;
    float* cinv = cmax + B_ * S_;

    short* PA = (short*)d_out;
    short* PB = PA + (size_t)B_ * S_ * 1024;

    void* args[] = {
        (void*)&A, (void*)&Bm, (void*)&PA, (void*)&PB, (void*)&Va, (void*)&Vb,
        (void*)&E, (void*)&rmax, (void*)&rinv, (void*)&cmax, (void*)&cinv,
        (void*)&Ma, (void*)&Mb
    };
    hipError_t err = hipLaunchCooperativeKernel((void*)k_mega, dim3(256),
                                                dim3(256), args, 0, stream);
    if (err != hipSuccess) {
        // Fallback: verified R4 multi-kernel pipeline.
        k_prep  <<<dim3(8, 8, 64),    256, 0, stream>>>(A, Bm, PA, PB, Va, Vb);
        k_gemm_e<<<dim3(4, 4, 32),    256, 0, stream>>>(PA, PB, E);
        k_rstats<<<dim3(B_ * S_ / 4), 256, 0, stream>>>(E, rmax, rinv);
        k_cstats<<<dim3(B_ * 8),      256, 0, stream>>>(E, cmax, cinv);
        k_pv    <<<dim3(2048),        256, 0, stream>>>(E, rmax, rinv, cmax, cinv,
                                                        Va, Vb, A, Bm, Ma, Mb);
    }
}

// Round 7
// 512.575 us; speedup vs baseline: 1.2008x; 1.2008x over previous
//
#include <hip/hip_runtime.h>
#include <hip/hip_bf16.h>
#include <math.h>

#define B_   32
#define S_   512
#define SxS  (S_ * S_)
#define LOG2E 1.4426950408889634f

using frag_ab = __attribute__((ext_vector_type(8))) short;   // 8 bf16 = 4 VGPR
using frag_cd = __attribute__((ext_vector_type(4))) float;   // 4 fp32 acc

__device__ inline short f2bf(float x) {
    __hip_bfloat16 h = __float2bfloat16(x);
    return *reinterpret_cast<short*>(&h);
}
__device__ inline float bf2f(short s) {
    __hip_bfloat16 h = *reinterpret_cast<__hip_bfloat16*>(&s);
    return __bfloat162float(h);
}
__device__ __forceinline__ int swz(int r) { return (r ^ (r >> 3)) & 7; }

// ---------------------------------------------------------------------------
// k_prep (unchanged, verified): reads A/B fp32 once. Produces:
//   1) PA/PB: packed hi/lo bf16 planes (PA pre-scaled LOG2E).
//      P[row][W (32 k)][slot: 2q=hi,2q+1=lo, stored at slot^(row&7)]
//   2) Va/Vb: bf16 transposed V-planes Vp[d][64-i window][chunk^(d&7)].
// ---------------------------------------------------------------------------
__global__ __launch_bounds__(256) void k_prep(const float* __restrict__ A,
                                              const float* __restrict__ Bm,
                                              short* __restrict__ PA,
                                              short* __restrict__ PB,
                                              short* __restrict__ Va,
                                              short* __restrict__ Vb)
{
    const int z   = blockIdx.z;
    const int b   = z & 31;
    const int isB = z >> 5;
    const float* X = (isB ? Bm : A) + (size_t)b * SxS;
    short* P  = (isB ? PB : PA) + (size_t)b * (S_ * 1024);
    short* Vp = (isB ? Vb : Va) + (size_t)b * SxS;
    const float scale = isB ? 1.0f : LOG2E;

    const int i0 = blockIdx.y * 64, d0 = blockIdx.x * 64;

    __shared__ short T[64][72];

    const int sl = threadIdx.x & 7;
    const int il = threadIdx.x >> 3;

    #pragma unroll
    for (int p = 0; p < 2; ++p) {
        const int i    = il + 32 * p;
        const int rowg = i0 + i;
        const float* src = X + (size_t)rowg * S_ + d0 + sl * 8;
        const float4 v0 = *(const float4*)(src);
        const float4 v1 = *(const float4*)(src + 4);

        T[sl * 8 + 0][i] = f2bf(v0.x); T[sl * 8 + 1][i] = f2bf(v0.y);
        T[sl * 8 + 2][i] = f2bf(v0.z); T[sl * 8 + 3][i] = f2bf(v0.w);
        T[sl * 8 + 4][i] = f2bf(v1.x); T[sl * 8 + 5][i] = f2bf(v1.y);
        T[sl * 8 + 6][i] = f2bf(v1.z); T[sl * 8 + 7][i] = f2bf(v1.w);

        const float xs[8] = {v0.x, v0.y, v0.z, v0.w, v1.x, v1.y, v1.z, v1.w};
        frag_ab hi, lo;
        #pragma unroll
        for (int j = 0; j < 8; ++j) {
            const float x = xs[j] * scale;
            const short h = f2bf(x);
            hi[j] = h;
            lo[j] = f2bf(x - bf2f(h));
        }
        const int W = (d0 >> 5) + (sl >> 2);
        const int q = sl & 3;
        short* base = P + (size_t)rowg * 1024 + W * 64;
        *(frag_ab*)(base + (((2 * q)     ^ (rowg & 7)) * 8)) = hi;
        *(frag_ab*)(base + (((2 * q + 1) ^ (rowg & 7)) * 8)) = lo;
    }
    __syncthreads();

    const int pc = threadIdx.x & 7, dl = threadIdx.x >> 3;
    #pragma unroll
    for (int p = 0; p < 2; ++p) {
        const int d  = dl + 32 * p;
        const int dg = d0 + d;
        frag_ab t = *(const frag_ab*)&T[d][pc * 8];
        *(frag_ab*)(Vp + (size_t)dg * 512 + i0 + ((pc ^ (dg & 7)) * 8)) = t;
    }
}

// ---------------------------------------------------------------------------
// k_gemm_e: e' = (LOG2E*A)·B^T via hi/lo bf16 MFMA.
// NO LDS, NO BARRIERS: fragments read per-lane directly from the L2-resident
// swizzled PA/PB planes (rowg&7 == m&7, so chunk offsets are lane-constant).
// The compiler pipelines loads across K-steps with counted vmcnt.
// ---------------------------------------------------------------------------
__global__ __launch_bounds__(256) void k_gemm_e(const short* __restrict__ PA,
                                                const short* __restrict__ PB,
                                                float* __restrict__ E)
{
    const int lin     = blockIdx.x + (blockIdx.y << 2) + (blockIdx.z << 4);
    const int logical = ((lin & 7) << 6) + (lin >> 3);
    const int b  = logical >> 4;
    const int i0 = ((logical >> 2) & 3) * 128;
    const int j0 = (logical & 3) * 128;

    const short* Ab = PA + (size_t)b * (S_ * 1024);
    const short* Bb = PB + (size_t)b * (S_ * 1024);
    float* Eb = E + (size_t)b * SxS;

    const int tid  = threadIdx.x;
    const int wave = tid >> 6, lane = tid & 63;
    const int wr   = wave >> 1, wc = wave & 1;
    const int q    = lane >> 4, m = lane & 15;
    const int mx7  = m & 7;
    const int chi  = ((2 * q)     ^ mx7) * 8;   // hi-chunk byte-slot (lane-const)
    const int clo  = ((2 * q + 1) ^ mx7) * 8;   // lo-chunk

    const short* arow[4];
    const short* brow[4];
    #pragma unroll
    for (int t = 0; t < 4; ++t) {
        arow[t] = Ab + (size_t)(i0 + wr * 64 + t * 16 + m) * 1024;
        brow[t] = Bb + (size_t)(j0 + wc * 64 + t * 16 + m) * 1024;
    }

    frag_cd zero = {0.f, 0.f, 0.f, 0.f};
    frag_cd acc[4][4];
    #pragma unroll
    for (int i = 0; i < 4; ++i)
        #pragma unroll
        for (int j = 0; j < 4; ++j) acc[i][j] = zero;

    for (int k0 = 0; k0 < S_; k0 += 32) {
        const int off = (k0 >> 5) * 64;
        frag_ab ah[4], al[4], bh[4], bl[4];
        #pragma unroll
        for (int t = 0; t < 4; ++t) {
            ah[t] = *(const frag_ab*)(arow[t] + off + chi);
            al[t] = *(const frag_ab*)(arow[t] + off + clo);
            bh[t] = *(const frag_ab*)(brow[t] + off + chi);
            bl[t] = *(const frag_ab*)(brow[t] + off + clo);
        }
        #pragma unroll
        for (int mt = 0; mt < 4; ++mt)
            #pragma unroll
            for (int nt = 0; nt < 4; ++nt) {
                acc[mt][nt] = __builtin_amdgcn_mfma_f32_16x16x32_bf16(ah[mt], bh[nt], acc[mt][nt], 0, 0, 0);
                acc[mt][nt] = __builtin_amdgcn_mfma_f32_16x16x32_bf16(ah[mt], bl[nt], acc[mt][nt], 0, 0, 0);
                acc[mt][nt] = __builtin_amdgcn_mfma_f32_16x16x32_bf16(al[mt], bh[nt], acc[mt][nt], 0, 0, 0);
            }
    }

    #pragma unroll
    for (int mt = 0; mt < 4; ++mt)
        #pragma unroll
        for (int nt = 0; nt < 4; ++nt) {
            const int rb  = i0 + wr * 64 + mt * 16 + q * 4;
            const int col = j0 + wc * 64 + nt * 16 + m;
            Eb[(size_t)(rb + 0) * S_ + col] = acc[mt][nt][0];
            Eb[(size_t)(rb + 1) * S_ + col] = acc[mt][nt][1];
            Eb[(size_t)(rb + 2) * S_ + col] = acc[mt][nt][2];
            Eb[(size_t)(rb + 3) * S_ + col] = acc[mt][nt][3];
        }
}

// ---------------------------------------------------------------------------
// k_rstats: per-row max and 1/sum(exp2) over E. One wave per row.
// ---------------------------------------------------------------------------
__global__ __launch_bounds__(256) void k_rstats(const float* __restrict__ E,
                                                float* __restrict__ rmax,
                                                float* __restrict__ rinv)
{
    const int row  = blockIdx.x * 4 + (threadIdx.x >> 6);
    const int lane = threadIdx.x & 63;
    const float* er = E + (size_t)row * S_;

    float4 v0 = *(const float4*)(er + lane * 4);
    float4 v1 = *(const float4*)(er + 256 + lane * 4);

    float m = fmaxf(fmaxf(fmaxf(v0.x, v0.y), fmaxf(v0.z, v0.w)),
                    fmaxf(fmaxf(v1.x, v1.y), fmaxf(v1.z, v1.w)));
    #pragma unroll
    for (int off = 32; off >= 1; off >>= 1)
        m = fmaxf(m, __shfl_xor(m, off));

    float s = exp2f(v0.x - m) + exp2f(v0.y - m)
            + exp2f(v0.z - m) + exp2f(v0.w - m)
            + exp2f(v1.x - m) + exp2f(v1.y - m)
            + exp2f(v1.z - m) + exp2f(v1.w - m);
    #pragma unroll
    for (int off = 32; off >= 1; off >>= 1)
        s += __shfl_xor(s, off);

    if (lane == 0) { rmax[row] = m; rinv[row] = 1.0f / s; }
}

// ---------------------------------------------------------------------------
// k_cstats: per-col max and 1/sum(exp2) over E.
// ---------------------------------------------------------------------------
__global__ __launch_bounds__(256) void k_cstats(const float* __restrict__ E,
                                                float* __restrict__ cmax,
                                                float* __restrict__ cinv)
{
    const int b  = blockIdx.x >> 3;
    const int s0 = (blockIdx.x & 7) * 64;
    const float* Eb = E + (size_t)b * SxS;

    __shared__ float scr[32][64];
    __shared__ float mS[64];

    const int tid = threadIdx.x;
    const int ib  = tid >> 3;
    const int sub = tid & 7;

    float pm[8];
    #pragma unroll
    for (int c = 0; c < 8; ++c) pm[c] = -INFINITY;
    for (int ii = 0; ii < 16; ++ii) {
        const float* p = Eb + (size_t)(ib * 16 + ii) * S_ + s0 + sub * 8;
        const float4 u  = *(const float4*)p;
        const float4 u2 = *(const float4*)(p + 4);
        pm[0] = fmaxf(pm[0], u.x);  pm[1] = fmaxf(pm[1], u.y);
        pm[2] = fmaxf(pm[2], u.z);  pm[3] = fmaxf(pm[3], u.w);
        pm[4] = fmaxf(pm[4], u2.x); pm[5] = fmaxf(pm[5], u2.y);
        pm[6] = fmaxf(pm[6], u2.z); pm[7] = fmaxf(pm[7], u2.w);
    }
    #pragma unroll
    for (int c = 0; c < 8; ++c) scr[ib][sub * 8 + c] = pm[c];
    __syncthreads();
    if (tid < 64) {
        float v = scr[0][tid];
        #pragma unroll
        for (int k = 1; k < 32; ++k) v = fmaxf(v, scr[k][tid]);
        mS[tid] = v;
        cmax[b * S_ + s0 + tid] = v;
    }
    __syncthreads();

    float ps[8];
    #pragma unroll
    for (int c = 0; c < 8; ++c) ps[c] = 0.f;
    for (int ii = 0; ii < 16; ++ii) {
        const float* p = Eb + (size_t)(ib * 16 + ii) * S_ + s0 + sub * 8;
        const float4 u  = *(const float4*)p;
        const float4 u2 = *(const float4*)(p + 4);
        const float xs[8] = {u.x, u.y, u.z, u.w, u2.x, u2.y, u2.z, u2.w};
        #pragma unroll
        for (int c = 0; c < 8; ++c) ps[c] += exp2f(xs[c] - mS[sub * 8 + c]);
    }
    __syncthreads();
    #pragma unroll
    for (int c = 0; c < 8; ++c) scr[ib][sub * 8 + c] = ps[c];
    __syncthreads();
    if (tid < 64) {
        float v = 0.f;
        #pragma unroll
        for (int k = 0; k < 32; ++k) v += scr[k][tid];
        cinv[b * S_ + s0 + tid] = 1.0f / v;
    }
}

// ---------------------------------------------------------------------------
// k_pv: C[32 rows][256 cols] = P · V. P built once in LDS (one exp pass,
// 32 KB), then a BARRIER-FREE K-loop: V fragments read per-lane directly
// from the L2-resident swizzled V-plane (d&7 == m&7 -> lane-const offsets).
// LDS 32 KB -> 4-5 blocks/CU. Fused 4-section epilogue. Both sides.
// ---------------------------------------------------------------------------
__global__ __launch_bounds__(256) void k_pv(const float* __restrict__ E,
                                            const float* __restrict__ rmx_,
                                            const float* __restrict__ rin_,
                                            const float* __restrict__ cmx_,
                                            const float* __restrict__ cin_,
                                            const short* __restrict__ Va,
                                            const short* __restrict__ Vb,
                                            const float* __restrict__ A,
                                            const float* __restrict__ Bm,
                                            float* __restrict__ Ma,
                                            float* __restrict__ Mb)
{
    const int lin = blockIdx.x;                       // 0..2047
    const int wg  = ((lin & 7) << 8) | (lin >> 3);    // XCD swizzle (bijective)
    const int side = wg >> 10;
    const int b    = (wg >> 5) & 31;
    const int rs   = (wg >> 1) & 15;
    const int dh   = wg & 1;
    const int s0   = rs * 32;

    const float* Eb  = E + (size_t)b * SxS;
    const float* pmx = (side ? cmx_ : rmx_) + b * S_;
    const float* piv = (side ? cin_ : rin_) + b * S_;
    const short* Vg  = (side ? Va : Vb) + (size_t)b * SxS;
    const float* Xb  = (side ? Bm : A) + (size_t)b * SxS;
    float* Ob = (side ? Mb : Ma) + (size_t)b * S_ * 2048;

    __shared__ __align__(16) short Pl[32][512];   // 32 KB
    __shared__ float riS[32];

    const int tid = threadIdx.x;
    const int wv  = tid >> 6, lane = tid & 63;
    const int q   = lane >> 4, m = lane & 15;
    const int mx7 = m & 7;

    if (tid < 32) riS[tid] = piv[s0 + tid];

    // ---------------- Phase A: build P strip in LDS (one exp pass) --------
    if (side == 0) {
        const int rl = tid >> 3, sub = tid & 7;
        const float mx = pmx[s0 + rl];
        const float* er = Eb + (size_t)(s0 + rl) * S_;
        const int sl = (sub ^ swz(rl)) * 8;
        #pragma unroll
        for (int fi = 0; fi < 8; ++fi) {
            const float* p = er + sub * 8 + fi * 64;
            const float4 u  = *(const float4*)p;
            const float4 u2 = *(const float4*)(p + 4);
            const float xs[8] = {u.x, u.y, u.z, u.w, u2.x, u2.y, u2.z, u2.w};
            frag_ab pb;
            #pragma unroll
            for (int j = 0; j < 8; ++j) pb[j] = f2bf(exp2f(xs[j] - mx));
            *(frag_ab*)&Pl[rl][fi * 64 + sl] = pb;
        }
    } else {
        const int ib = tid >> 2, cs = tid & 3;
        float mloc[8];
        #pragma unroll
        for (int c = 0; c < 8; ++c) mloc[c] = pmx[s0 + cs * 8 + c];
        frag_ab pb[8];
        #pragma unroll
        for (int ii = 0; ii < 8; ++ii) {
            const float* p = Eb + (size_t)(ib * 8 + ii) * S_ + s0 + cs * 8;
            const float4 u  = *(const float4*)p;
            const float4 u2 = *(const float4*)(p + 4);
            const float xs[8] = {u.x, u.y, u.z, u.w, u2.x, u2.y, u2.z, u2.w};
            #pragma unroll
            for (int c = 0; c < 8; ++c)
                pb[c][ii] = f2bf(exp2f(xs[c] - mloc[c]));
        }
        #pragma unroll
        for (int c = 0; c < 8; ++c) {
            const int cl = cs * 8 + c;
            *(frag_ab*)&Pl[cl][((ib ^ swz(cl)) & 63) * 8] = pb[c];
        }
    }
    __syncthreads();    // Pl + riS ready; no further barriers in this kernel

    // ---------------- Phase B: C = P · V (barrier-free) --------------------
    const short* vrow[4];
    int psw[2];
    #pragma unroll
    for (int t = 0; t < 4; ++t)
        vrow[t] = Vg + (size_t)(dh * 256 + wv * 64 + t * 16 + m) * 512;
    #pragma unroll
    for (int t = 0; t < 2; ++t)
        psw[t] = swz(t * 16 + m);

    frag_cd zero = {0.f, 0.f, 0.f, 0.f};
    frag_cd acc[2][4];
    #pragma unroll
    for (int i = 0; i < 2; ++i)
        #pragma unroll
        for (int j = 0; j < 4; ++j) acc[i][j] = zero;

    for (int k0 = 0; k0 < S_; k0 += 64) {
        #pragma unroll
        for (int kk = 0; kk < 2; ++kk) {
            const int c = kk * 4 + q;
            frag_ab af[2], bf[4];
            #pragma unroll
            for (int t = 0; t < 2; ++t)
                af[t] = *(const frag_ab*)&Pl[t * 16 + m][k0 + ((c ^ psw[t]) * 8)];
            #pragma unroll
            for (int t = 0; t < 4; ++t)
                bf[t] = *(const frag_ab*)(vrow[t] + k0 + ((c ^ mx7) * 8));
            #pragma unroll
            for (int mt = 0; mt < 2; ++mt)
                #pragma unroll
                for (int nt = 0; nt < 4; ++nt)
                    acc[mt][nt] = __builtin_amdgcn_mfma_f32_16x16x32_bf16(af[mt], bf[nt], acc[mt][nt], 0, 0, 0);
        }
    }

    // ---------------- Epilogue --------------------------------------------
    #pragma unroll
    for (int mt = 0; mt < 2; ++mt)
        #pragma unroll
        for (int nt = 0; nt < 4; ++nt) {
            const int colg = dh * 256 + wv * 64 + nt * 16 + m;
            #pragma unroll
            for (int rr = 0; rr < 4; ++rr) {
                const int rl   = mt * 16 + q * 4 + rr;
                const int rowg = s0 + rl;
                const float at = acc[mt][nt][rr] * riS[rl];
                const float xv = Xb[(size_t)rowg * S_ + colg];
                float* o = Ob + (size_t)rowg * 2048 + colg;
                o[0]    = xv;
                o[512]  = at;
                o[1024] = xv - at;
                o[1536] = xv * at;
            }
        }
}

// ---------------------------------------------------------------------------
extern "C" void kernel_launch(void* const* d_in, const int* in_sizes, int n_in,
                              void* d_out, int out_size, void* d_ws, size_t ws_size,
                              hipStream_t stream)
{
    const float* A  = (const float*)d_in[0];   // a_bar [32,512,512]
    const float* Bm = (const float*)d_in[1];   // b_bar [32,512,512]
    float* Ma = (float*)d_out;                             // [32,512,2048]
    float* Mb = Ma + (size_t)B_ * S_ * 2048;               // [32,512,2048]

    // ws: E 33.5 MB + Va/Vb 16.8 MB each + stats ~0.26 MB
    float* E    = (float*)d_ws;
    short* Va   = (short*)(E + (size_t)B_ * SxS);
    short* Vb   = Va + (size_t)B_ * SxS;
    float* rmax = (float*)(Vb + (size_t)B_ * SxS);
    float* rinv = rmax + B_ * S_;
    float* cmax = rinv + B_ * S_;
    float* cinv = cmax + B_ * S_;

    // PA/PB hi/lo planes scratch in the OUTPUT buffer (dead after k_gemm_e).
    short* PA = (short*)d_out;
    short* PB = PA + (size_t)B_ * S_ * 1024;

    k_prep  <<<dim3(8, 8, 64),    256, 0, stream>>>(A, Bm, PA, PB, Va, Vb);
    k_gemm_e<<<dim3(4, 4, 32),    256, 0, stream>>>(PA, PB, E);
    k_rstats<<<dim3(B_ * S_ / 4), 256, 0, stream>>>(E, rmax, rinv);
    k_cstats<<<dim3(B_ * 8),      256, 0, stream>>>(E, cmax, cinv);
    k_pv    <<<dim3(2048),        256, 0, stream>>>(E, rmax, rinv, cmax, cinv,
                                                    Va, Vb, A, Bm, Ma, Mb);
}

// Round 9
// 426.943 us; speedup vs baseline: 1.4417x; 1.2006x over previous
//
#include <hip/hip_runtime.h>
#include <hip/hip_bf16.h>
#include <math.h>

#define B_   32
#define S_   512
#define SxS  (S_ * S_)
#define LOG2E 1.4426950408889634f

using frag_ab = __attribute__((ext_vector_type(8))) short;   // 8 bf16 = 4 VGPR
using frag_cd = __attribute__((ext_vector_type(4))) float;   // 4 fp32 acc

__device__ inline short f2bf(float x) {
    __hip_bfloat16 h = __float2bfloat16(x);
    return *reinterpret_cast<short*>(&h);
}
__device__ inline float bf2f(short s) {
    __hip_bfloat16 h = *reinterpret_cast<__hip_bfloat16*>(&s);
    return __bfloat162float(h);
}
__device__ __forceinline__ int swz(int r) { return (r ^ (r >> 3)) & 7; }

// async global->LDS, 16B per lane. LDS dest must be wave-uniform base.
__device__ __forceinline__ void async16(const short* g, short* l) {
    __builtin_amdgcn_global_load_lds(
        (const __attribute__((address_space(1))) void*)g,
        (__attribute__((address_space(3))) void*)l,
        16, 0, 0);
}

// ---------------------------------------------------------------------------
// k_prep (unchanged, verified): reads A/B fp32 once. Produces:
//   1) PA/PB: packed hi/lo bf16 planes (PA pre-scaled LOG2E).
//   2) Va/Vb: bf16 transposed V-planes Vp[d][64-i window][chunk^(d&7)].
// ---------------------------------------------------------------------------
__global__ __launch_bounds__(256) void k_prep(const float* __restrict__ A,
                                              const float* __restrict__ Bm,
                                              short* __restrict__ PA,
                                              short* __restrict__ PB,
                                              short* __restrict__ Va,
                                              short* __restrict__ Vb)
{
    const int z   = blockIdx.z;
    const int b   = z & 31;
    const int isB = z >> 5;
    const float* X = (isB ? Bm : A) + (size_t)b * SxS;
    short* P  = (isB ? PB : PA) + (size_t)b * (S_ * 1024);
    short* Vp = (isB ? Vb : Va) + (size_t)b * SxS;
    const float scale = isB ? 1.0f : LOG2E;

    const int i0 = blockIdx.y * 64, d0 = blockIdx.x * 64;

    __shared__ short T[64][72];

    const int sl = threadIdx.x & 7;
    const int il = threadIdx.x >> 3;

    #pragma unroll
    for (int p = 0; p < 2; ++p) {
        const int i    = il + 32 * p;
        const int rowg = i0 + i;
        const float* src = X + (size_t)rowg * S_ + d0 + sl * 8;
        const float4 v0 = *(const float4*)(src);
        const float4 v1 = *(const float4*)(src + 4);

        T[sl * 8 + 0][i] = f2bf(v0.x); T[sl * 8 + 1][i] = f2bf(v0.y);
        T[sl * 8 + 2][i] = f2bf(v0.z); T[sl * 8 + 3][i] = f2bf(v0.w);
        T[sl * 8 + 4][i] = f2bf(v1.x); T[sl * 8 + 5][i] = f2bf(v1.y);
        T[sl * 8 + 6][i] = f2bf(v1.z); T[sl * 8 + 7][i] = f2bf(v1.w);

        const float xs[8] = {v0.x, v0.y, v0.z, v0.w, v1.x, v1.y, v1.z, v1.w};
        frag_ab hi, lo;
        #pragma unroll
        for (int j = 0; j < 8; ++j) {
            const float x = xs[j] * scale;
            const short h = f2bf(x);
            hi[j] = h;
            lo[j] = f2bf(x - bf2f(h));
        }
        const int W = (d0 >> 5) + (sl >> 2);
        const int q = sl & 3;
        short* base = P + (size_t)rowg * 1024 + W * 64;
        *(frag_ab*)(base + (((2 * q)     ^ (rowg & 7)) * 8)) = hi;
        *(frag_ab*)(base + (((2 * q + 1) ^ (rowg & 7)) * 8)) = lo;
    }
    __syncthreads();

    const int pc = threadIdx.x & 7, dl = threadIdx.x >> 3;
    #pragma unroll
    for (int p = 0; p < 2; ++p) {
        const int d  = dl + 32 * p;
        const int dg = d0 + d;
        frag_ab t = *(const frag_ab*)&T[d][pc * 8];
        *(frag_ab*)(Vp + (size_t)dg * 512 + i0 + ((pc ^ (dg & 7)) * 8)) = t;
    }
}

// ---------------------------------------------------------------------------
// k_gemm_e (R4 verified LDS-staged version): e' = (LOG2E*A)·B^T via hi/lo
// bf16 MFMA; global_load_lds staging, swizzled ds_read_b128, writes E.
// ---------------------------------------------------------------------------
__global__ __launch_bounds__(256) void k_gemm_e(const short* __restrict__ PA,
                                                const short* __restrict__ PB,
                                                float* __restrict__ E)
{
    const int lin     = blockIdx.x + (blockIdx.y << 2) + (blockIdx.z << 4);
    const int logical = ((lin & 7) << 6) + (lin >> 3);
    const int b  = logical >> 4;
    const int i0 = ((logical >> 2) & 3) * 128;
    const int j0 = (logical & 3) * 128;

    const short* Ab = PA + (size_t)b * (S_ * 1024);
    const short* Bb = PB + (size_t)b * (S_ * 1024);
    float* Eb = E + (size_t)b * SxS;

    __shared__ __align__(16) short As[128][64];
    __shared__ __align__(16) short Bs[128][64];

    const int tid  = threadIdx.x;
    const int wave = tid >> 6, lane = tid & 63;
    const int wr   = wave >> 1, wc = wave & 1;
    const int q    = lane >> 4, m = lane & 15;
    const int srow = lane >> 3, schunk = lane & 7;

    frag_cd zero = {0.f, 0.f, 0.f, 0.f};
    frag_cd acc[4][4];
    #pragma unroll
    for (int i = 0; i < 4; ++i)
        #pragma unroll
        for (int j = 0; j < 4; ++j) acc[i][j] = zero;

    for (int k0 = 0; k0 < S_; k0 += 32) {
        const int W = k0 >> 5;
        __syncthreads();
        #pragma unroll
        for (int p = 0; p < 4; ++p) {
            const int seg    = wave * 4 + p;
            const int rowg_a = i0 + seg * 8 + srow;
            const int rowg_b = j0 + seg * 8 + srow;
            async16(Ab + (size_t)rowg_a * 1024 + W * 64 + schunk * 8, &As[seg * 8][0]);
            async16(Bb + (size_t)rowg_b * 1024 + W * 64 + schunk * 8, &Bs[seg * 8][0]);
        }
        __syncthreads();

        frag_ab ah[4], al[4], bh[4], bl[4];
        #pragma unroll
        for (int t = 0; t < 4; ++t) {
            const int ra = wr * 64 + t * 16 + m;
            const int rb = wc * 64 + t * 16 + m;
            ah[t] = *(const frag_ab*)&As[ra][((2 * q)     ^ (ra & 7)) * 8];
            al[t] = *(const frag_ab*)&As[ra][((2 * q + 1) ^ (ra & 7)) * 8];
            bh[t] = *(const frag_ab*)&Bs[rb][((2 * q)     ^ (rb & 7)) * 8];
            bl[t] = *(const frag_ab*)&Bs[rb][((2 * q + 1) ^ (rb & 7)) * 8];
        }
        #pragma unroll
        for (int mt = 0; mt < 4; ++mt)
            #pragma unroll
            for (int nt = 0; nt < 4; ++nt) {
                acc[mt][nt] = __builtin_amdgcn_mfma_f32_16x16x32_bf16(ah[mt], bh[nt], acc[mt][nt], 0, 0, 0);
                acc[mt][nt] = __builtin_amdgcn_mfma_f32_16x16x32_bf16(ah[mt], bl[nt], acc[mt][nt], 0, 0, 0);
                acc[mt][nt] = __builtin_amdgcn_mfma_f32_16x16x32_bf16(al[mt], bh[nt], acc[mt][nt], 0, 0, 0);
            }
    }

    #pragma unroll
    for (int mt = 0; mt < 4; ++mt)
        #pragma unroll
        for (int nt = 0; nt < 4; ++nt) {
            const int rb  = i0 + wr * 64 + mt * 16 + q * 4;
            const int col = j0 + wc * 64 + nt * 16 + m;
            Eb[(size_t)(rb + 0) * S_ + col] = acc[mt][nt][0];
            Eb[(size_t)(rb + 1) * S_ + col] = acc[mt][nt][1];
            Eb[(size_t)(rb + 2) * S_ + col] = acc[mt][nt][2];
            Eb[(size_t)(rb + 3) * S_ + col] = acc[mt][nt][3];
        }
}

// ---------------------------------------------------------------------------
// k_stats: merged row-stats (blocks 0..4095) + col-stats (blocks 4096..4351).
// ---------------------------------------------------------------------------
__global__ __launch_bounds__(256) void k_stats(const float* __restrict__ E,
                                               float* __restrict__ rmax,
                                               float* __restrict__ rinv,
                                               float* __restrict__ cmax,
                                               float* __restrict__ cinv)
{
    const int bid = blockIdx.x;
    const int tid = threadIdx.x;

    if (bid < 4096) {
        // ---- row stats: one wave per row ----
        const int row  = bid * 4 + (tid >> 6);
        const int lane = tid & 63;
        const float* er = E + (size_t)row * S_;

        float4 v0 = *(const float4*)(er + lane * 4);
        float4 v1 = *(const float4*)(er + 256 + lane * 4);

        float m = fmaxf(fmaxf(fmaxf(v0.x, v0.y), fmaxf(v0.z, v0.w)),
                        fmaxf(fmaxf(v1.x, v1.y), fmaxf(v1.z, v1.w)));
        #pragma unroll
        for (int off = 32; off >= 1; off >>= 1)
            m = fmaxf(m, __shfl_xor(m, off));

        float s = exp2f(v0.x - m) + exp2f(v0.y - m)
                + exp2f(v0.z - m) + exp2f(v0.w - m)
                + exp2f(v1.x - m) + exp2f(v1.y - m)
                + exp2f(v1.z - m) + exp2f(v1.w - m);
        #pragma unroll
        for (int off = 32; off >= 1; off >>= 1)
            s += __shfl_xor(s, off);

        if (lane == 0) { rmax[row] = m; rinv[row] = 1.0f / s; }
        return;
    }

    // ---- col stats: block = (b, 64-col strip) ----
    __shared__ float scr[32][64];
    __shared__ float mS[64];

    const int cb = bid - 4096;
    const int b  = cb >> 3;
    const int s0 = (cb & 7) * 64;
    const float* Eb = E + (size_t)b * SxS;

    const int ib  = tid >> 3;
    const int sub = tid & 7;

    float pm[8];
    #pragma unroll
    for (int c = 0; c < 8; ++c) pm[c] = -INFINITY;
    for (int ii = 0; ii < 16; ++ii) {
        const float* p = Eb + (size_t)(ib * 16 + ii) * S_ + s0 + sub * 8;
        const float4 u  = *(const float4*)p;
        const float4 u2 = *(const float4*)(p + 4);
        pm[0] = fmaxf(pm[0], u.x);  pm[1] = fmaxf(pm[1], u.y);
        pm[2] = fmaxf(pm[2], u.z);  pm[3] = fmaxf(pm[3], u.w);
        pm[4] = fmaxf(pm[4], u2.x); pm[5] = fmaxf(pm[5], u2.y);
        pm[6] = fmaxf(pm[6], u2.z); pm[7] = fmaxf(pm[7], u2.w);
    }
    #pragma unroll
    for (int c = 0; c < 8; ++c) scr[ib][sub * 8 + c] = pm[c];
    __syncthreads();
    if (tid < 64) {
        float v = scr[0][tid];
        #pragma unroll
        for (int k = 1; k < 32; ++k) v = fmaxf(v, scr[k][tid]);
        mS[tid] = v;
        cmax[b * S_ + s0 + tid] = v;
    }
    __syncthreads();

    float ps[8];
    #pragma unroll
    for (int c = 0; c < 8; ++c) ps[c] = 0.f;
    for (int ii = 0; ii < 16; ++ii) {
        const float* p = Eb + (size_t)(ib * 16 + ii) * S_ + s0 + sub * 8;
        const float4 u  = *(const float4*)p;
        const float4 u2 = *(const float4*)(p + 4);
        const float xs[8] = {u.x, u.y, u.z, u.w, u2.x, u2.y, u2.z, u2.w};
        #pragma unroll
        for (int c = 0; c < 8; ++c) ps[c] += exp2f(xs[c] - mS[sub * 8 + c]);
    }
    __syncthreads();
    #pragma unroll
    for (int c = 0; c < 8; ++c) scr[ib][sub * 8 + c] = ps[c];
    __syncthreads();
    if (tid < 64) {
        float v = 0.f;
        #pragma unroll
        for (int k = 0; k < 32; ++k) v += scr[k][tid];
        cinv[b * S_ + s0 + tid] = 1.0f / v;
    }
}

// ---------------------------------------------------------------------------
// k_pv: C[32 rows][256 cols] = P · V (R4 staged K-loop), then an
// LDS-TRANSPOSED epilogue: C (pre-scaled) round-trips through the now-dead
// Pl/Vs LDS so each wave writes whole rows — float4 stores, 64 lanes x 16B
// = 1KB coalesced per instruction for all 4 output sections; X read as
// coalesced float4 too. LDS 64.1 KB -> 2 blocks/CU.
// ---------------------------------------------------------------------------
__global__ __launch_bounds__(256) void k_pv(const float* __restrict__ E,
                                            const float* __restrict__ rmx_,
                                            const float* __restrict__ rin_,
                                            const float* __restrict__ cmx_,
                                            const float* __restrict__ cin_,
                                            const short* __restrict__ Va,
                                            const short* __restrict__ Vb,
                                            const float* __restrict__ A,
                                            const float* __restrict__ Bm,
                                            float* __restrict__ Ma,
                                            float* __restrict__ Mb)
{
    const int lin = blockIdx.x;                       // 0..2047
    const int wg  = ((lin & 7) << 8) | (lin >> 3);    // bijective XCD swizzle
    const int side = wg >> 10;
    const int b    = (wg >> 5) & 31;
    const int rs   = (wg >> 1) & 15;
    const int dh   = wg & 1;
    const int s0   = rs * 32;

    const float* Eb  = E + (size_t)b * SxS;
    const float* pmx = (side ? cmx_ : rmx_) + b * S_;
    const float* piv = (side ? cin_ : rin_) + b * S_;
    const short* Vg  = (side ? Va : Vb) + (size_t)b * SxS;
    const float* Xb  = (side ? Bm : A) + (size_t)b * SxS;
    float* Ob = (side ? Mb : Ma) + (size_t)b * S_ * 2048;

    __shared__ __align__(16) char smem[65664];
    short (*Pl)[512] = (short(*)[512])smem;            // 32 KB
    short (*Vs)[64]  = (short(*)[64])(smem + 32768);   // 32 KB
    float* riS       = (float*)(smem + 65536);         // 128 B

    const int tid = threadIdx.x;
    const int wv  = tid >> 6, lane = tid & 63;
    const int q   = lane >> 4, m = lane & 15;

    if (tid < 32) riS[tid] = piv[s0 + tid];

    // ---------------- Phase A: build P strip in LDS (one exp pass) --------
    if (side == 0) {
        const int rl = tid >> 3, sub = tid & 7;
        const float mx = pmx[s0 + rl];
        const float* er = Eb + (size_t)(s0 + rl) * S_;
        const int sl = (sub ^ swz(rl)) * 8;
        #pragma unroll
        for (int fi = 0; fi < 8; ++fi) {
            const float* p = er + sub * 8 + fi * 64;
            const float4 u  = *(const float4*)p;
            const float4 u2 = *(const float4*)(p + 4);
            const float xs[8] = {u.x, u.y, u.z, u.w, u2.x, u2.y, u2.z, u2.w};
            frag_ab pb;
            #pragma unroll
            for (int j = 0; j < 8; ++j) pb[j] = f2bf(exp2f(xs[j] - mx));
            *(frag_ab*)&Pl[rl][fi * 64 + sl] = pb;
        }
    } else {
        const int ib = tid >> 2, cs = tid & 3;
        float mloc[8];
        #pragma unroll
        for (int c = 0; c < 8; ++c) mloc[c] = pmx[s0 + cs * 8 + c];
        frag_ab pb[8];
        #pragma unroll
        for (int ii = 0; ii < 8; ++ii) {
            const float* p = Eb + (size_t)(ib * 8 + ii) * S_ + s0 + cs * 8;
            const float4 u  = *(const float4*)p;
            const float4 u2 = *(const float4*)(p + 4);
            const float xs[8] = {u.x, u.y, u.z, u.w, u2.x, u2.y, u2.z, u2.w};
            #pragma unroll
            for (int c = 0; c < 8; ++c)
                pb[c][ii] = f2bf(exp2f(xs[c] - mloc[c]));
        }
        #pragma unroll
        for (int c = 0; c < 8; ++c) {
            const int cl = cs * 8 + c;
            *(frag_ab*)&Pl[cl][((ib ^ swz(cl)) & 63) * 8] = pb[c];
        }
    }

    // ---------------- Phase B: C = P · V (R4 staged loop) -----------------
    frag_cd zero = {0.f, 0.f, 0.f, 0.f};
    frag_cd acc[2][4];
    #pragma unroll
    for (int i = 0; i < 2; ++i)
        #pragma unroll
        for (int j = 0; j < 4; ++j) acc[i][j] = zero;

    for (int k0 = 0; k0 < S_; k0 += 64) {
        __syncthreads();
        #pragma unroll
        for (int p = 0; p < 8; ++p) {
            const int seg = p * 32 + wv * 8;              // wave-uniform
            const int d   = dh * 256 + seg + (lane >> 3);
            async16(Vg + (size_t)d * 512 + k0 + (lane & 7) * 8, &Vs[seg][0]);
        }
        __syncthreads();

        #pragma unroll
        for (int kk = 0; kk < 2; ++kk) {
            frag_ab af[2], bf[4];
            #pragma unroll
            for (int t = 0; t < 2; ++t) {
                const int ra = t * 16 + m;
                af[t] = *(const frag_ab*)&Pl[ra][k0 + (((kk * 4 + q) ^ swz(ra)) * 8)];
            }
            #pragma unroll
            for (int t = 0; t < 4; ++t) {
                const int dl = wv * 64 + t * 16 + m;
                bf[t] = *(const frag_ab*)&Vs[dl][(((kk * 4 + q) ^ (dl & 7)) * 8)];
            }
            #pragma unroll
            for (int mt = 0; mt < 2; ++mt)
                #pragma unroll
                for (int nt = 0; nt < 4; ++nt)
                    acc[mt][nt] = __builtin_amdgcn_mfma_f32_16x16x32_bf16(af[mt], bf[nt], acc[mt][nt], 0, 0, 0);
        }
    }

    // ---------------- Epilogue: LDS transpose -> coalesced float4 ---------
    __syncthreads();                       // Pl/Vs dead; safe to overwrite
    float* Ct = (float*)smem;              // [32][pitch 260] fp32 = 33.3 KB
    #pragma unroll
    for (int mt = 0; mt < 2; ++mt)
        #pragma unroll
        for (int nt = 0; nt < 4; ++nt)
            #pragma unroll
            for (int rr = 0; rr < 4; ++rr) {
                const int rl = mt * 16 + q * 4 + rr;
                Ct[rl * 260 + wv * 64 + nt * 16 + m] = acc[mt][nt][rr] * riS[rl];
            }
    __syncthreads();

    #pragma unroll
    for (int p = 0; p < 8; ++p) {
        const int rl   = wv * 8 + p;                  // wave owns 8 rows
        const int rowg = s0 + rl;
        const float4 at4 = *(const float4*)&Ct[rl * 260 + lane * 4];
        const int colg = dh * 256 + lane * 4;
        const float4 xv4 = *(const float4*)(Xb + (size_t)rowg * S_ + colg);
        float* o = Ob + (size_t)rowg * 2048 + colg;
        *(float4*)(o)        = xv4;
        *(float4*)(o + 512)  = at4;
        *(float4*)(o + 1024) = make_float4(xv4.x - at4.x, xv4.y - at4.y,
                                           xv4.z - at4.z, xv4.w - at4.w);
        *(float4*)(o + 1536) = make_float4(xv4.x * at4.x, xv4.y * at4.y,
                                           xv4.z * at4.z, xv4.w * at4.w);
    }
}

// ---------------------------------------------------------------------------
extern "C" void kernel_launch(void* const* d_in, const int* in_sizes, int n_in,
                              void* d_out, int out_size, void* d_ws, size_t ws_size,
                              hipStream_t stream)
{
    const float* A  = (const float*)d_in[0];   // a_bar [32,512,512]
    const float* Bm = (const float*)d_in[1];   // b_bar [32,512,512]
    float* Ma = (float*)d_out;                             // [32,512,2048]
    float* Mb = Ma + (size_t)B_ * S_ * 2048;               // [32,512,2048]

    // ws: E 33.5 MB + Va/Vb 16.8 MB each + stats ~0.26 MB
    float* E    = (float*)d_ws;
    short* Va   = (short*)(E + (size_t)B_ * SxS);
    short* Vb   = Va + (size_t)B_ * SxS;
    float* rmax = (float*)(Vb + (size_t)B_ * SxS);
    float* rinv = rmax + B_ * S_;
    float* cmax = rinv + B_ * S_;
    float* cinv = cmax + B_ * S_;

    // PA/PB hi/lo planes scratch in the OUTPUT buffer (dead after k_gemm_e).
    short* PA = (short*)d_out;
    short* PB = PA + (size_t)B_ * S_ * 1024;

    k_prep  <<<dim3(8, 8, 64), 256, 0, stream>>>(A, Bm, PA, PB, Va, Vb);
    k_gemm_e<<<dim3(4, 4, 32), 256, 0, stream>>>(PA, PB, E);
    k_stats <<<dim3(4352),     256, 0, stream>>>(E, rmax, rinv, cmax, cinv);
    k_pv    <<<dim3(2048),     256, 0, stream>>>(E, rmax, rinv, cmax, cinv,
                                                 Va, Vb, A, Bm, Ma, Mb);
}